// Round 8
// baseline (232.625 us; speedup 1.0000x reference)
//
#include <hip/hip_runtime.h>

#define DINF 128
#define DHID 128
#define DOUTF 64

#define CHUNK 12544   // histogram slots per LDS chunk (49 KB)
#define NCHUNK 4      // ceil(50000 / 12544)
#define ECH 16        // edge slices for deg_priv
#define ESL 4         // edge slices for cnt_hist
#define NGRP 8        // CSR groups (~XCDs)
#define CAP 96        // max staged edges per node (Poisson(24); P(>96)~0)

typedef unsigned short ushort_t;
typedef unsigned int uint_t;
typedef __attribute__((ext_vector_type(8))) short bf16x8;
typedef __attribute__((ext_vector_type(4))) float f32x4;

__device__ __forceinline__ ushort_t f2b(float x) {   // f32 -> bf16 RNE
    uint_t u = __float_as_uint(x);
    u += 0x7fffu + ((u >> 16) & 1u);
    return (ushort_t)(u >> 16);
}
__device__ __forceinline__ float b2f_lo(uint_t u) { return __uint_as_float(u << 16); }
__device__ __forceinline__ float b2f_hi(uint_t u) { return __uint_as_float(u & 0xffff0000u); }

// ---- LDS-privatized degree histogram for all 4 index arrays (for weights) ----
__global__ void deg_priv_kernel(const int* __restrict__ s1, const int* __restrict__ d1,
                                const int* __restrict__ s2, const int* __restrict__ d2,
                                int* __restrict__ deg, int N, int ne) {
    extern __shared__ int h[];
    int t = threadIdx.x;
    for (int j = t; j < CHUNK; j += 1024) h[j] = 0;
    __syncthreads();

    const int* p = blockIdx.z == 0 ? s1 : blockIdx.z == 1 ? d1 : blockIdx.z == 2 ? s2 : d2;
    int lo = blockIdx.y * CHUNK;
    int per = (ne + ECH - 1) / ECH;
    int e0 = blockIdx.x * per;
    int e1 = e0 + per < ne ? e0 + per : ne;
    for (int i = e0 + t; i < e1; i += 1024) {
        int idx = p[i] - lo;
        if ((unsigned)idx < (unsigned)CHUNK) atomicAdd(&h[idx], 1);
    }
    __syncthreads();

    int* dz = deg + (size_t)blockIdx.z * N;
    for (int j = t; j < CHUNK; j += 1024) {
        int node = lo + j;
        int v = h[j];
        if (v && node < N) atomicAdd(&dz[node], v);
    }
}

// ---- per-(group,node) combined in-degree counts, group = fill-block linear id & 7 ----
// grid (NCHUNK, NGRP, ESL), block 1024, LDS CHUNK ints. cnt layout: [esl][g][node].
__global__ void cnt_hist_kernel(const int* __restrict__ dst1, const int* __restrict__ dst2,
                                int* __restrict__ cnt, int N, int ne, int eb) {
    extern __shared__ int h[];
    int t = threadIdx.x;
    for (int j = t; j < CHUNK; j += 1024) h[j] = 0;
    __syncthreads();

    int lo = blockIdx.x * CHUNK;
    int g = blockIdx.y;
    int q = blockIdx.z;

    for (int graph = 0; graph < 2; ++graph) {
        const int* dst = graph ? dst2 : dst1;
        int base = graph * eb;
        int r0 = (g - base) & 7;            // first run of this group
        if (r0 >= eb) continue;
        int K = (eb - r0 + 7) / 8;          // runs in this group
        int k0 = (int)(((long long)K * q) / ESL);
        int k1 = (int)(((long long)K * (q + 1)) / ESL);
        for (int idx = k0 * 256 + t; idx < k1 * 256; idx += 1024) {
            int r = r0 + 8 * (idx >> 8);
            int i = r * 256 + (idx & 255);
            if (i < ne) {
                int d = dst[i] - lo;
                if ((unsigned)d < (unsigned)CHUNK) atomicAdd(&h[d], 1);
            }
        }
    }
    __syncthreads();

    int* cq = cnt + (size_t)q * (8 * (size_t)N) + (size_t)g * N;
    for (int j = t; j < CHUNK; j += 1024) {
        int node = lo + j;
        if (node < N) cq[node] = h[j];
    }
}

// ---- scan phase 1 over m=8N entries; input = sum of ESL cnt slices ----
__global__ void scan1_kernel(const int* __restrict__ cnt, int* __restrict__ offs,
                             int* __restrict__ bsum, int m) {
    __shared__ int warp_sums[4];
    int t = threadIdx.x;
    int lane = t & 63;
    int wid = t >> 6;
    int base = blockIdx.x * 1024 + t * 4;

    int v[4];
    int tot = 0;
    #pragma unroll
    for (int j = 0; j < 4; ++j) {
        int i = base + j;
        int d = 0;
        if (i < m) d = cnt[i] + cnt[m + i] + cnt[2 * (size_t)m + i] + cnt[3 * (size_t)m + i];
        v[j] = d; tot += d;
    }
    int x = tot;
    #pragma unroll
    for (int off = 1; off < 64; off <<= 1) {
        int y = __shfl_up(x, off, 64);
        if (lane >= off) x += y;
    }
    if (lane == 63) warp_sums[wid] = x;
    __syncthreads();
    int wbase = 0;
    for (int w = 0; w < wid; ++w) wbase += warp_sums[w];
    int run = wbase + x - tot;
    #pragma unroll
    for (int j = 0; j < 4; ++j) {
        int i = base + j;
        if (i < m) offs[i] = run;
        run += v[j];
    }
    if (t == 255) bsum[blockIdx.x] = run;
}

// ---- scan phase 2 ----
__global__ void scan2_kernel(int* __restrict__ bsum, int* __restrict__ offs, int nb, int m) {
    int lane = threadIdx.x;
    int run = 0;
    for (int base = 0; base < nb; base += 64) {
        int i = base + lane;
        int v = (i < nb) ? bsum[i] : 0;
        int x = v;
        #pragma unroll
        for (int off = 1; off < 64; off <<= 1) {
            int y = __shfl_up(x, off, 64);
            if (lane >= off) x += y;
        }
        if (i < nb) bsum[i] = run + x - v;
        run += __shfl(x, 63, 64);
    }
    if (lane == 0) offs[m] = run;
}

// ---- scan phase 3 ----
__global__ void scan3_kernel(int* __restrict__ offs, int* __restrict__ cursor,
                             const int* __restrict__ bsum, int m) {
    int base = blockIdx.x * 1024 + threadIdx.x * 4;
    int add = bsum[blockIdx.x];
    #pragma unroll
    for (int j = 0; j < 4; ++j) {
        int i = base + j;
        if (i < m) { int o = offs[i] + add; offs[i] = o; cursor[i] = o; }
    }
}

// ---- CSR fill, group-major regions (group = linear block id & 7) ----
__global__ void fill2_kernel(const int* __restrict__ src1, const int* __restrict__ dst1,
                             const int* __restrict__ src2, const int* __restrict__ dst2,
                             const int* __restrict__ deg, const float* __restrict__ attn,
                             int* __restrict__ cursor, int2* __restrict__ csr,
                             int N, int ne, int eb) {
    int b = blockIdx.x;
    int i = b * 256 + threadIdx.x;
    if (i >= ne) return;
    int gr = blockIdx.y;
    int g = ((gr ? eb : 0) + b) & 7;
    const int* src = gr == 0 ? src1 : src2;
    const int* dst = gr == 0 ? dst1 : dst2;
    const int* deg_out = deg + (size_t)(2 * gr) * N;
    const int* deg_in  = deg + (size_t)(2 * gr + 1) * N;
    int s = src[i];
    int d = dst[i];
    int pos = atomicAdd(&cursor[(size_t)g * N + d], 1);
    float w = attn[gr] * rsqrtf(fmaxf((float)deg_in[d], 1.0f))
                       * rsqrtf(fmaxf((float)deg_out[s], 1.0f));
    csr[pos] = make_int2(s, __float_as_int(w));
}

// ---- W convert+transpose, both weights in one launch ----
__global__ void wconv2_kernel(const float* __restrict__ W1, const float* __restrict__ W2,
                              ushort_t* __restrict__ Wt1, ushort_t* __restrict__ Wt2) {
    int tid = blockIdx.x * 256 + threadIdx.x;
    if (tid < 128 * 128) {
        int ncol = tid / 128, k = tid % 128;
        Wt1[tid] = f2b(W1[(size_t)k * 128 + ncol]);
    } else if (tid < 128 * 128 + 64 * 128) {
        int t2 = tid - 128 * 128;
        int ncol = t2 / 128, k = t2 % 128;
        Wt2[t2] = f2b(W2[(size_t)k * 64 + ncol]);
    }
}

// ---- MFMA GEMM: Y[n,NOUT](bf16) = X[n,128] @ W  (Wt = bf16 W^T [NOUT][128]) ----
template<int NOUT, bool F32IN>
__global__ __launch_bounds__(256) void mfma_gemm_kernel(const void* __restrict__ Xv,
                                                        const ushort_t* __restrict__ Wt,
                                                        ushort_t* __restrict__ Y, int n) {
    constexpr int CT = NOUT / 16;
    const int lane = threadIdx.x & 63;
    const int wv = threadIdx.x >> 6;
    const int row0 = blockIdx.x * 64 + wv * 16;
    const int arow = row0 + (lane & 15);
    const int arc = arow < n ? arow : (n - 1);

    f32x4 acc[CT];
    #pragma unroll
    for (int ct = 0; ct < CT; ++ct) acc[ct] = (f32x4)(0.f);

    #pragma unroll
    for (int kk = 0; kk < 4; ++kk) {
        const int k0 = kk * 32 + (lane >> 4) * 8;
        bf16x8 a;
        if (F32IN) {
            const float* xp = (const float*)Xv + (size_t)arc * 128 + k0;
            float4 u0 = *(const float4*)xp;
            float4 u1 = *(const float4*)(xp + 4);
            a[0] = (short)f2b(u0.x); a[1] = (short)f2b(u0.y);
            a[2] = (short)f2b(u0.z); a[3] = (short)f2b(u0.w);
            a[4] = (short)f2b(u1.x); a[5] = (short)f2b(u1.y);
            a[6] = (short)f2b(u1.z); a[7] = (short)f2b(u1.w);
        } else {
            a = *(const bf16x8*)((const ushort_t*)Xv + (size_t)arc * 128 + k0);
        }
        #pragma unroll
        for (int ct = 0; ct < CT; ++ct) {
            bf16x8 b = *(const bf16x8*)(Wt + (size_t)(ct * 16 + (lane & 15)) * 128 + k0);
            acc[ct] = __builtin_amdgcn_mfma_f32_16x16x32_bf16(a, b, acc[ct], 0, 0, 0);
        }
    }

    const int orow0 = row0 + (lane >> 4) * 4;
    const int col = lane & 15;
    #pragma unroll
    for (int ct = 0; ct < CT; ++ct) {
        #pragma unroll
        for (int r = 0; r < 4; ++r) {
            int row = orow0 + r;
            if (row < n) Y[(size_t)row * NOUT + ct * 16 + col] = f2b(acc[ct][r]);
        }
    }
}

// ---- shared staging helper: merge the node's 8 group-segments into LDS ----
// Returns total (may exceed CAP; [0,min(total,CAP)) staged in el).
__device__ __forceinline__ int stage_edges(const int* __restrict__ offs,
                                           const int2* __restrict__ csr,
                                           int2* __restrict__ el,   // per-wave CAP entries
                                           int n, int wid, int lane, bool valid,
                                           int c0[8], int c1[8], int eg[8]) {
    int myE0 = 0, myLen = 0;
    if (valid && lane < 8) {
        myE0 = offs[(size_t)lane * n + wid];
        myLen = offs[(size_t)lane * n + wid + 1] - myE0;
    }
    int inc = myLen;
    #pragma unroll
    for (int off = 1; off < 8; off <<= 1) {
        int y = __shfl_up(inc, off, 8);
        if ((lane & 7) >= off) inc += y;
    }
    int exc = inc - myLen;
    int total = __shfl(inc, 7, 64);
    #pragma unroll
    for (int g = 0; g < 8; ++g) {
        c0[g] = __shfl(exc, g, 64);
        c1[g] = __shfl(inc, g, 64);
        eg[g] = __shfl(myE0, g, 64);
    }
    int tot = total < CAP ? total : CAP;
    for (int k = lane; k < tot; k += 64) {
        int ea = 0;
        #pragma unroll
        for (int g = 0; g < 8; ++g)
            if (k >= c0[g] && k < c1[g]) ea = eg[g] + (k - c0[g]);
        el[k] = csr[ea];
    }
    return total;
}

// ---- agg D=128: LDS-staged edge list, 8 gathers in flight; uint (2 bf16)/lane ----
__global__ void agg128_kernel(const ushort_t* __restrict__ V, const int* __restrict__ offs,
                              const int2* __restrict__ csr, const float* __restrict__ bias,
                              const float* __restrict__ attn, uint_t* __restrict__ out, int n) {
    __shared__ int2 el[4][CAP];
    int wv = threadIdx.x >> 6;
    int lane = threadIdx.x & 63;
    int wid = blockIdx.x * 4 + wv;
    bool valid = wid < n;

    int c0[8], c1[8], eg[8];
    int total = stage_edges(offs, csr, el[wv], n, valid ? wid : 0, lane, valid, c0, c1, eg);
    __syncthreads();
    int tot = total < CAP ? total : CAP;

    float acc0 = 0.f, acc1 = 0.f;
    int e = 0;
    for (; e + 8 <= tot; e += 8) {
        int2 cv[8]; uint_t u[8];
        #pragma unroll
        for (int j = 0; j < 8; ++j) cv[j] = el[wv][e + j];
        #pragma unroll
        for (int j = 0; j < 8; ++j)
            u[j] = ((const uint_t*)(V + (size_t)cv[j].x * 128))[lane];
        #pragma unroll
        for (int j = 0; j < 8; ++j) {
            float w = __int_as_float(cv[j].y);
            acc0 += w * b2f_lo(u[j]); acc1 += w * b2f_hi(u[j]);
        }
    }
    if (e + 4 <= tot) {
        int2 cv[4]; uint_t u[4];
        #pragma unroll
        for (int j = 0; j < 4; ++j) cv[j] = el[wv][e + j];
        #pragma unroll
        for (int j = 0; j < 4; ++j)
            u[j] = ((const uint_t*)(V + (size_t)cv[j].x * 128))[lane];
        #pragma unroll
        for (int j = 0; j < 4; ++j) {
            float w = __int_as_float(cv[j].y);
            acc0 += w * b2f_lo(u[j]); acc1 += w * b2f_hi(u[j]);
        }
        e += 4;
    }
    for (; e < tot; ++e) {
        int2 cv = el[wv][e];
        float w = __int_as_float(cv.y);
        uint_t u = ((const uint_t*)(V + (size_t)cv.x * 128))[lane];
        acc0 += w * b2f_lo(u); acc1 += w * b2f_hi(u);
    }
    if (total > CAP) {   // overflow fallback (statistically never)
        #pragma unroll
        for (int g = 0; g < 8; ++g) {
            int s0 = c0[g] > CAP ? c0[g] : CAP;
            for (int k = s0; k < c1[g]; ++k) {
                int2 cv = csr[eg[g] + (k - c0[g])];
                float w = __int_as_float(cv.y);
                uint_t u = ((const uint_t*)(V + (size_t)cv.x * 128))[lane];
                acc0 += w * b2f_lo(u); acc1 += w * b2f_hi(u);
            }
        }
    }

    if (valid) {
        float bs = attn[0] + attn[1];
        float2 bb = ((const float2*)bias)[lane];
        float o0 = acc0 + bs * bb.x;
        float o1 = acc1 + bs * bb.y;
        out[(size_t)wid * 64 + lane] = (uint_t)f2b(o0) | ((uint_t)f2b(o1) << 16);
    }
}

// ---- agg D=64: LDS-staged; half-wave per edge (32 lanes x 4B = 128B row) ----
__global__ void agg64_kernel(const ushort_t* __restrict__ V, const int* __restrict__ offs,
                             const int2* __restrict__ csr, const float* __restrict__ bias,
                             const float* __restrict__ attn, float* __restrict__ out, int n) {
    __shared__ int2 el[4][CAP];
    int wv = threadIdx.x >> 6;
    int lane = threadIdx.x & 63;
    int half = lane >> 5;
    int hl = lane & 31;
    int wid = blockIdx.x * 4 + wv;
    bool valid = wid < n;

    int c0[8], c1[8], eg[8];
    int total = stage_edges(offs, csr, el[wv], n, valid ? wid : 0, lane, valid, c0, c1, eg);
    __syncthreads();
    int tot = total < CAP ? total : CAP;

    float acc0 = 0.f, acc1 = 0.f;
    int e = 0;
    for (; e + 8 <= tot; e += 8) {
        int2 cv[4]; uint_t u[4];
        #pragma unroll
        for (int j = 0; j < 4; ++j) cv[j] = el[wv][e + 2 * j + half];
        #pragma unroll
        for (int j = 0; j < 4; ++j)
            u[j] = ((const uint_t*)(V + (size_t)cv[j].x * 64))[hl];
        #pragma unroll
        for (int j = 0; j < 4; ++j) {
            float w = __int_as_float(cv[j].y);
            acc0 += w * b2f_lo(u[j]); acc1 += w * b2f_hi(u[j]);
        }
    }
    for (; e + 2 <= tot; e += 2) {
        int2 cv = el[wv][e + half];
        float w = __int_as_float(cv.y);
        uint_t u = ((const uint_t*)(V + (size_t)cv.x * 64))[hl];
        acc0 += w * b2f_lo(u); acc1 += w * b2f_hi(u);
    }
    if (e < tot && half == 0) {
        int2 cv = el[wv][e];
        float w = __int_as_float(cv.y);
        uint_t u = ((const uint_t*)(V + (size_t)cv.x * 64))[hl];
        acc0 += w * b2f_lo(u); acc1 += w * b2f_hi(u);
    }
    if (total > CAP && half == 0) {   // overflow fallback
        #pragma unroll
        for (int g = 0; g < 8; ++g) {
            int s0 = c0[g] > CAP ? c0[g] : CAP;
            for (int k = s0; k < c1[g]; ++k) {
                int2 cv = csr[eg[g] + (k - c0[g])];
                float w = __int_as_float(cv.y);
                uint_t u = ((const uint_t*)(V + (size_t)cv.x * 64))[hl];
                acc0 += w * b2f_lo(u); acc1 += w * b2f_hi(u);
            }
        }
    }

    acc0 += __shfl_xor(acc0, 32, 64);
    acc1 += __shfl_xor(acc1, 32, 64);

    if (valid && half == 0) {
        float bs = attn[0] + attn[1];
        float2 bb = ((const float2*)bias)[hl];
        float2 o = make_float2(acc0 + bs * bb.x, acc1 + bs * bb.y);
        ((float2*)(out + (size_t)wid * 64))[hl] = o;
    }
}

extern "C" void kernel_launch(void* const* d_in, const int* in_sizes, int n_in,
                              void* d_out, int out_size, void* d_ws, size_t ws_size,
                              hipStream_t stream) {
    const float* feat = (const float*)d_in[0];
    const int* src1   = (const int*)d_in[1];
    const int* dst1   = (const int*)d_in[2];
    const int* src2   = (const int*)d_in[3];
    const int* dst2   = (const int*)d_in[4];
    const float* attn = (const float*)d_in[5];
    const float* W1   = (const float*)d_in[6];
    const float* b1   = (const float*)d_in[7];
    const float* W2   = (const float*)d_in[8];
    const float* b2   = (const float*)d_in[9];
    float* out = (float*)d_out;

    const int N  = in_sizes[0] / DINF;     // 50000
    const int NE = in_sizes[1];            // 600000
    const int eb = (NE + 255) / 256;       // fill blocks per graph (2344, %8==0)
    const int M  = NGRP * N;               // grouped offs length
    const int NB2 = (M + 1023) / 1024;     // scan blocks

    // workspace layout:
    // Wt1 | Wt2 | A bf16[N*128] | B bf16[N*128] | C bf16[N*64] | csr int2[2NE] |
    // offs[M+1] | cursor[M] | deg[4N] | cnt[ESL*M] | bsum[NB2]
    ushort_t* Wt1 = (ushort_t*)d_ws;
    ushort_t* Wt2 = Wt1 + 128 * 128;
    ushort_t* A   = Wt2 + 64 * 128;
    ushort_t* B   = A + (size_t)N * DHID;
    ushort_t* C   = B + (size_t)N * DHID;
    int2* csr   = (int2*)(C + (size_t)N * DOUTF);
    int* offs   = (int*)(csr + 2 * (size_t)NE);
    int* cursor = offs + (M + 1);
    int* deg    = cursor + M;
    int* cnt    = deg + 4 * (size_t)N;
    int* bsum   = cnt + (size_t)ESL * M;

    hipMemsetAsync(deg, 0, sizeof(int) * 4 * (size_t)N, stream);

    wconv2_kernel<<<(128 * 128 + 64 * 128 + 255) / 256, 256, 0, stream>>>(W1, W2, Wt1, Wt2);

    deg_priv_kernel<<<dim3(ECH, NCHUNK, 4), 1024, CHUNK * sizeof(int), stream>>>(
        src1, dst1, src2, dst2, deg, N, NE);

    cnt_hist_kernel<<<dim3(NCHUNK, NGRP, ESL), 1024, CHUNK * sizeof(int), stream>>>(
        dst1, dst2, cnt, N, NE, eb);

    scan1_kernel<<<NB2, 256, 0, stream>>>(cnt, offs, bsum, M);
    scan2_kernel<<<1, 64, 0, stream>>>(bsum, offs, NB2, M);
    scan3_kernel<<<NB2, 256, 0, stream>>>(offs, cursor, bsum, M);

    fill2_kernel<<<dim3(eb, 2), 256, 0, stream>>>(src1, dst1, src2, dst2, deg, attn,
                                                  cursor, csr, N, NE, eb);

    int gb = (N + 63) / 64;
    int ab = (N + 3) / 4;
    // layer 1: A = bf16(feat @ W1) ; B = bf16(agg(A) + (a0+a1)*b1)
    mfma_gemm_kernel<DHID, true><<<gb, 256, 0, stream>>>(feat, Wt1, A, N);
    agg128_kernel<<<ab, 256, 0, stream>>>(A, offs, csr, b1, attn, (uint_t*)B, N);

    // layer 2: C = bf16(B @ W2) ; out = agg(C) + (a0+a1)*b2  (f32)
    mfma_gemm_kernel<DOUTF, false><<<gb, 256, 0, stream>>>(B, Wt2, C, N);
    agg64_kernel<<<ab, 256, 0, stream>>>(C, offs, csr, b2, attn, out, N);
}